// Round 4
// baseline (1568.601 us; speedup 1.0000x reference)
//
#include <hip/hip_runtime.h>
#include <cstdint>

#define NM 20
#define HS 72          // bf16 row stride (144 B, 16B-aligned for ds_read_b128)
#define MS 68          // mbuf f32 row stride (272 B, 16B-aligned, 2-way banks)

typedef __attribute__((ext_vector_type(8))) short bf16x8;
typedef __attribute__((ext_vector_type(4))) float f32x4;

#define MFMA(A, Bf, C) __builtin_amdgcn_mfma_f32_16x16x32_bf16((A), (Bf), (C), 0, 0, 0)

// ---- fragment-packed weights (bf16), built by prep kernel every launch ----
#define F_NE    0        // 1c x 4nb   (K=16 pad 32, N=64)
#define F_M1W1  2048     // 4c x 4nb   (K=128, N=64)
#define F_M1W2  10240    // 2c x 4nb
#define F_M2W1  14336    // 4c x 4nb
#define F_M2W2  22528    // 2c x 4nb
#define F_WIH   26624    // 3c x 12nb  (K=72 pad 96, N=192)
#define F_WHH   45056    // 2c x 12nb  (K=64, N=192)
#define F_PQ    57344    // 2c x 4nb
#define F_PACK  61440    // 2c x 2nb   (K=64, N=28 pad 32: op|c1|c2)
#define F_PK    63488    // 2c x 4nb
#define F_TOTAL 67584

__device__ __align__(16) short g_fr[F_TOTAL];

__device__ __forceinline__ short bf16rn(float x) {
  unsigned u = __float_as_uint(x);
  u += 0x7fffu + ((u >> 16) & 1u);
  return (short)(u >> 16);
}
__device__ __forceinline__ float bf2f(short s) {
  return __uint_as_float(((unsigned)(unsigned short)s) << 16);
}

#define LDF(off) (*(const bf16x8*)(g_fr + (off) + lane * 8))

// ---------------- prep: pack weights into B-fragment lane order ----------------
#define BUILD(OFS, CH, NBL, GETEXPR)                                   \
  for (int i = t; i < (CH) * (NBL) * 512; i += T) {                    \
    int j = i & 7, ln = (i >> 3) & 63, f = i >> 9;                     \
    int c = f / (NBL), nb = f % (NBL);                                 \
    int k = c * 32 + ((ln >> 4)) * 8 + j;                              \
    int n = nb * 16 + (ln & 15);                                       \
    (void)c; (void)k; (void)n;                                         \
    g_fr[(OFS) + i] = bf16rn(GETEXPR);                                 \
  }

__global__ void __launch_bounds__(256)
prep_frag(const float* __restrict__ ne_w,
          const float* __restrict__ m1w1, const float* __restrict__ m1w2,
          const float* __restrict__ m2w1, const float* __restrict__ m2w2,
          const float* __restrict__ wih,  const float* __restrict__ whh,
          const float* __restrict__ pqw,  const float* __restrict__ opw,
          const float* __restrict__ c1w,  const float* __restrict__ c2w,
          const float* __restrict__ pkw)
{
  const int t = blockIdx.x * blockDim.x + threadIdx.x;
  const int T = gridDim.x * blockDim.x;
  BUILD(F_NE,   1, 4,  (k < 16 ? ne_w[n * 16 + k] : 0.f))
  BUILD(F_M1W1, 4, 4,  m1w1[n * 128 + k])
  BUILD(F_M1W2, 2, 4,  m1w2[n * 64 + k])
  BUILD(F_M2W1, 4, 4,  m2w1[n * 128 + k])
  BUILD(F_M2W2, 2, 4,  m2w2[n * 64 + k])
  BUILD(F_WIH,  3, 12, (k < 72 ? wih[n * 72 + k] : 0.f))
  BUILD(F_WHH,  2, 12, whh[n * 64 + k])
  BUILD(F_PQ,   2, 4,  pqw[n * 64 + k])
  BUILD(F_PACK, 2, 2,  (n < 8 ? opw[n * 64 + k]
                        : n < 18 ? c1w[(n - 8) * 64 + k]
                        : n < 28 ? c2w[(n - 18) * 64 + k] : 0.f))
  BUILD(F_PK,   2, 4,  pkw[n * 64 + k])
}

// ---------------- MP block (per-wave: nodes n = wv, wv+8, wv+16) ----------------
__device__ __forceinline__ void mp_stage(
    short (*hbuf)[16][HS], short* tsc_w, float (*min_)[MS], float (*mout_)[MS],
    int w1off, int w2off,
    const float* __restrict__ B1P, const float* __restrict__ B2P,
    const float* __restrict__ LGP, const float* __restrict__ LBP,
    const int* nnrow, float iv, int wv, int lane, int l15, int q)
{
  const f32x4 zf4 = {0.f, 0.f, 0.f, 0.f};
  // msg A-frags from f32 sums (scale by 1/nn of this row's batch = l15)
  bf16x8 am0, am1;
  {
    const float* mrow = &min_[l15][0];
    #pragma unroll
    for (int j = 0; j < 8; j++) {
      am0[j] = bf16rn(mrow[q * 8 + j] * iv);
      am1[j] = bf16rn(mrow[32 + q * 8 + j] * iv);
    }
  }
  // msg half of W1 is node-independent: compute once
  f32x4 tmsg[4];
  #pragma unroll
  for (int nb = 0; nb < 4; nb++) {
    f32x4 t = MFMA(am0, LDF(w1off + (2 * 4 + nb) * 512), zf4);
    tmsg[nb] = MFMA(am1, LDF(w1off + (3 * 4 + nb) * 512), t);
  }
  float b1v[4], b2v[4], lgv[4], lbv[4];
  #pragma unroll
  for (int nb = 0; nb < 4; nb++) {
    int cc = l15 + 16 * nb;
    b1v[nb] = B1P[cc]; b2v[nb] = B2P[cc];
    lgv[nb] = LGP[cc]; lbv[nb] = LBP[cc];
  }
  for (int n = wv; n < NM; n += 8) {
    bf16x8 a0 = *(const bf16x8*)&hbuf[n][l15][q * 8];
    bf16x8 a1 = *(const bf16x8*)&hbuf[n][l15][32 + q * 8];
    f32x4 tout[4];
    #pragma unroll
    for (int nb = 0; nb < 4; nb++) {
      f32x4 acc = MFMA(a0, LDF(w1off + (0 * 4 + nb) * 512), tmsg[nb]);
      tout[nb]  = MFMA(a1, LDF(w1off + (1 * 4 + nb) * 512), acc);
    }
    #pragma unroll
    for (int nb = 0; nb < 4; nb++)
      #pragma unroll
      for (int i = 0; i < 4; i++)
        tsc_w[(q * 4 + i) * HS + l15 + 16 * nb] =
          bf16rn(fmaxf(tout[nb][i] + b1v[nb], 0.f));
    asm volatile("s_waitcnt lgkmcnt(0)" ::: "memory");
    bf16x8 t0 = *(const bf16x8*)&tsc_w[l15 * HS + q * 8];
    bf16x8 t1 = *(const bf16x8*)&tsc_w[l15 * HS + 32 + q * 8];
    f32x4 h1[4];
    #pragma unroll
    for (int nb = 0; nb < 4; nb++) {
      f32x4 acc = MFMA(t0, LDF(w2off + (0 * 4 + nb) * 512), zf4);
      h1[nb]    = MFMA(t1, LDF(w2off + (1 * 4 + nb) * 512), acc);
    }
    #pragma unroll
    for (int i = 0; i < 4; i++) {
      float y[4]; float s = 0.f;
      #pragma unroll
      for (int nb = 0; nb < 4; nb++) {
        float h0v = bf2f(hbuf[n][q * 4 + i][l15 + 16 * nb]);
        y[nb] = h1[nb][i] + b2v[nb] + h0v; s += y[nb];
      }
      s += __shfl_xor(s, 1, 64); s += __shfl_xor(s, 2, 64);
      s += __shfl_xor(s, 4, 64); s += __shfl_xor(s, 8, 64);
      float mu = s * 0.015625f; float vs = 0.f;
      #pragma unroll
      for (int nb = 0; nb < 4; nb++) { y[nb] -= mu; vs += y[nb] * y[nb]; }
      vs += __shfl_xor(vs, 1, 64); vs += __shfl_xor(vs, 2, 64);
      vs += __shfl_xor(vs, 4, 64); vs += __shfl_xor(vs, 8, 64);
      float rstd = rsqrtf(vs * 0.015625f + 1e-5f);
      float mfv = (n < nnrow[i]) ? 1.f : 0.f;
      #pragma unroll
      for (int nb = 0; nb < 4; nb++) {
        float hv = (y[nb] * rstd * lgv[nb] + lbv[nb]) * mfv;
        hbuf[n][q * 4 + i][l15 + 16 * nb] = bf16rn(hv);
        atomicAdd(&mout_[q * 4 + i][l15 + 16 * nb], hv);   // hv==0 when masked
      }
    }
  }
}

// ---------------- main fused kernel: 16 batch / block, 8 waves ----------------
__global__ void __launch_bounds__(512)
msp_mfma(const float* __restrict__ nf, const int* __restrict__ nnp,
         const float* __restrict__ rnn, const float* __restrict__ poh,
         const float* __restrict__ ne_b,
         const float* __restrict__ m1b1, const float* __restrict__ m1b2,
         const float* __restrict__ n1g, const float* __restrict__ n1b,
         const float* __restrict__ m2b1, const float* __restrict__ m2b2,
         const float* __restrict__ n2g, const float* __restrict__ n2b,
         const float* __restrict__ bih, const float* __restrict__ bhh,
         const float* __restrict__ opb, const float* __restrict__ c1b,
         const float* __restrict__ c2b, const float* __restrict__ pqb,
         const float* __restrict__ pkb,
         float* __restrict__ out, int B)
{
  __shared__ __align__(16) short hbuf[NM][16][HS];   // 46080 B
  __shared__ __align__(16) short tsc[8][16][HS];     // 18432 B (t-scratch / GRU exchange)
  __shared__ __align__(16) float mbuf[3][16][MS];    // 13056 B (msg1/msg2/gv f32 sums)
  __shared__ __align__(16) short nsbuf[16][HS];      // 2304 B (new_state bf16)
  __shared__ int   nn_sh[16];
  __shared__ float inv_sh[16];

  const int tid  = threadIdx.x;
  const int wv   = tid >> 6;
  const int lane = tid & 63;
  const int l15  = lane & 15;
  const int q    = lane >> 4;
  const int b0   = blockIdx.x * 16;

  for (int i = tid; i < 3 * 16 * MS; i += 512) ((float*)mbuf)[i] = 0.f;
  if (tid < 16) { int v = nnp[b0 + tid]; nn_sh[tid] = v; inv_sh[tid] = 1.0f / (float)v; }
  __syncthreads();

  int nnrow[4];
  #pragma unroll
  for (int i = 0; i < 4; i++) nnrow[i] = nn_sh[q * 4 + i];
  const float iv = inv_sh[l15];

  const f32x4 zf4 = {0.f, 0.f, 0.f, 0.f};

  // ================= stage E: h0 = nf @ ne_w^T + ne_b =================
  {
    bf16x8 nef[4]; float neb[4];
    #pragma unroll
    for (int nb = 0; nb < 4; nb++) { nef[nb] = LDF(F_NE + nb * 512); neb[nb] = ne_b[l15 + 16 * nb]; }
    for (int n = wv; n < NM; n += 8) {
      bf16x8 a;
      #pragma unroll
      for (int j = 0; j < 8; j++) a[j] = 0;
      if (q < 2) {
        const float* p = nf + ((size_t)(b0 + l15) * NM + n) * 16 + q * 8;
        #pragma unroll
        for (int j = 0; j < 8; j++) a[j] = bf16rn(p[j]);
      }
      #pragma unroll
      for (int nb = 0; nb < 4; nb++) {
        f32x4 acc = MFMA(a, nef[nb], zf4);
        #pragma unroll
        for (int i = 0; i < 4; i++) {
          float v = acc[i] + neb[nb];
          hbuf[n][q * 4 + i][l15 + 16 * nb] = bf16rn(v);
          if (n < nnrow[i]) atomicAdd(&mbuf[0][q * 4 + i][l15 + 16 * nb], v);
        }
      }
    }
  }
  __syncthreads();

  mp_stage(hbuf, (short*)&tsc[wv][0][0], mbuf[0], mbuf[1], F_M1W1, F_M1W2,
           m1b1, m1b2, n1g, n1b, nnrow, iv, wv, lane, l15, q);
  __syncthreads();
  mp_stage(hbuf, (short*)&tsc[wv][0][0], mbuf[1], mbuf[2], F_M2W1, F_M2W2,
           m2b1, m2b2, n2g, n2b, nnrow, iv, wv, lane, l15, q);
  __syncthreads();

  // ================= GRU: MFMA phase (12 tiles over 8 waves) =================
  short* Xb = (short*)&tsc[0][0][0];     // X=gi+gh raw  [8][16][18]
  short* Gi = Xb + 8 * 288;              // gin raw      [4][16][18]
  short* Gh = Gi + 4 * 288;              // ghn raw      [4][16][18]
  {
    bf16x8 ax0, ax1, ax2, ah0, ah1;
    {
      const float* gr = &mbuf[2][l15][0];
      #pragma unroll
      for (int j = 0; j < 8; j++) {
        ax0[j] = bf16rn(gr[q * 8 + j] * iv);
        ax1[j] = bf16rn(gr[32 + q * 8 + j] * iv);
      }
    }
    #pragma unroll
    for (int j = 0; j < 8; j++) ax2[j] = 0;
    if (q == 0) {
      const float* pp = poh + (size_t)(b0 + l15) * 8;
      #pragma unroll
      for (int j = 0; j < 8; j++) ax2[j] = bf16rn(pp[j]);
    }
    {
      const float* pr = rnn + (size_t)(b0 + l15) * 64;
      #pragma unroll
      for (int j = 0; j < 8; j++) { ah0[j] = bf16rn(pr[q * 8 + j]); ah1[j] = bf16rn(pr[32 + q * 8 + j]); }
    }
    for (int nb = wv; nb < 12; nb += 8) {
      f32x4 a = MFMA(ax0, LDF(F_WIH + (0 * 12 + nb) * 512), zf4);
      a = MFMA(ax1, LDF(F_WIH + (1 * 12 + nb) * 512), a);
      a = MFMA(ax2, LDF(F_WIH + (2 * 12 + nb) * 512), a);
      f32x4 h = MFMA(ah0, LDF(F_WHH + (0 * 12 + nb) * 512), zf4);
      h = MFMA(ah1, LDF(F_WHH + (1 * 12 + nb) * 512), h);
      if (nb < 8) {
        #pragma unroll
        for (int i = 0; i < 4; i++)
          Xb[nb * 288 + (q * 4 + i) * 18 + l15] = bf16rn(a[i] + h[i]);
      } else {
        #pragma unroll
        for (int i = 0; i < 4; i++) {
          Gi[(nb - 8) * 288 + (q * 4 + i) * 18 + l15] = bf16rn(a[i]);
          Gh[(nb - 8) * 288 + (q * 4 + i) * 18 + l15] = bf16rn(h[i]);
        }
      }
    }
  }
  __syncthreads();

  // ================= GRU: pointwise gates (1024 items / 512 threads) =================
  #pragma unroll
  for (int rep = 0; rep < 2; rep++) {
    int it = tid + rep * 512;
    int row = it >> 6, col = it & 63;
    int nb = col >> 4, c16 = col & 15;
    float Xr = bf2f(Xb[nb * 288 + row * 18 + c16]) + bih[col] + bhh[col];
    float Xz = bf2f(Xb[(4 + nb) * 288 + row * 18 + c16]) + bih[64 + col] + bhh[64 + col];
    float gn = bf2f(Gi[nb * 288 + row * 18 + c16]) + bih[128 + col];
    float hn = bf2f(Gh[nb * 288 + row * 18 + c16]) + bhh[128 + col];
    float r = 1.f / (1.f + expf(-Xr));
    float z = 1.f / (1.f + expf(-Xz));
    float ng = tanhf(gn + r * hn);
    float st = rnn[(size_t)(b0 + row) * 64 + col];
    float ns = (1.f - z) * ng + z * st;
    out[(size_t)B * 48 + (size_t)(b0 + row) * 64 + col] = ns;
    nsbuf[row][col] = bf16rn(ns);
  }
  __syncthreads();

  // ================= heads: q (waves 0-3), op/c1/c2 (waves 4-5) =================
  if (wv < 6) {
    bf16x8 an0 = *(const bf16x8*)&nsbuf[l15][q * 8];
    bf16x8 an1 = *(const bf16x8*)&nsbuf[l15][32 + q * 8];
    if (wv < 4) {
      f32x4 a = MFMA(an0, LDF(F_PQ + (0 * 4 + wv) * 512), zf4);
      a = MFMA(an1, LDF(F_PQ + (1 * 4 + wv) * 512), a);
      float bias = pqb[l15 + 16 * wv];
      #pragma unroll
      for (int i = 0; i < 4; i++)
        mbuf[0][q * 4 + i][l15 + 16 * wv] = a[i] + bias;   // q head, f32
    } else {
      int nb = wv - 4;
      f32x4 a = MFMA(an0, LDF(F_PACK + (0 * 2 + nb) * 512), zf4);
      a = MFMA(an1, LDF(F_PACK + (1 * 2 + nb) * 512), a);
      int col = l15 + 16 * nb;
      float bias = col < 8 ? opb[col] : col < 18 ? c1b[col - 8] : col < 28 ? c2b[col - 18] : 0.f;
      #pragma unroll
      for (int i = 0; i < 4; i++) {
        int b = b0 + q * 4 + i; float v = a[i] + bias;
        if (col < 8)       out[(size_t)b * 8 + col] = v;
        else if (col < 18) out[(size_t)B * 8 + (size_t)b * 10 + (col - 8)] = v;
        else if (col < 28) out[(size_t)B * 18 + (size_t)b * 10 + (col - 18)] = v;
      }
    }
  }
  __syncthreads();

  // ================= pointer logits =================
  {
    float pkbv[4], qv[4][4];
    #pragma unroll
    for (int nb = 0; nb < 4; nb++) {
      pkbv[nb] = pkb[l15 + 16 * nb];
      #pragma unroll
      for (int i = 0; i < 4; i++) qv[nb][i] = mbuf[0][q * 4 + i][l15 + 16 * nb];
    }
    for (int n = wv; n < NM; n += 8) {
      bf16x8 a0 = *(const bf16x8*)&hbuf[n][l15][q * 8];
      bf16x8 a1 = *(const bf16x8*)&hbuf[n][l15][32 + q * 8];
      f32x4 kk[4];
      #pragma unroll
      for (int nb = 0; nb < 4; nb++) {
        f32x4 acc = MFMA(a0, LDF(F_PK + (0 * 4 + nb) * 512), zf4);
        kk[nb]    = MFMA(a1, LDF(F_PK + (1 * 4 + nb) * 512), acc);
      }
      #pragma unroll
      for (int i = 0; i < 4; i++) {
        float tt = 0.f;
        #pragma unroll
        for (int nb = 0; nb < 4; nb++) tt += qv[nb][i] * (kk[nb][i] + pkbv[nb]);
        tt += __shfl_xor(tt, 1, 64); tt += __shfl_xor(tt, 2, 64);
        tt += __shfl_xor(tt, 4, 64); tt += __shfl_xor(tt, 8, 64);
        if (l15 == 0) {
          int b = b0 + q * 4 + i;
          out[(size_t)B * 28 + (size_t)b * 20 + n] = (n < nnrow[i]) ? tt : -1e9f;
        }
      }
    }
  }
}

extern "C" void kernel_launch(void* const* d_in, const int* in_sizes, int n_in,
                              void* d_out, int out_size, void* d_ws, size_t ws_size,
                              hipStream_t stream)
{
  (void)n_in; (void)out_size; (void)d_ws; (void)ws_size;
  const float* nf   = (const float*)d_in[0];
  const int*   nnp  = (const int*)  d_in[1];
  const float* rnn  = (const float*)d_in[2];
  const float* poh  = (const float*)d_in[3];
  const float* ne_w = (const float*)d_in[4];
  const float* ne_b = (const float*)d_in[5];
  const float* m1w1 = (const float*)d_in[6];
  const float* m1b1 = (const float*)d_in[7];
  const float* m1w2 = (const float*)d_in[8];
  const float* m1b2 = (const float*)d_in[9];
  const float* n1g  = (const float*)d_in[10];
  const float* n1b  = (const float*)d_in[11];
  const float* m2w1 = (const float*)d_in[12];
  const float* m2b1 = (const float*)d_in[13];
  const float* m2w2 = (const float*)d_in[14];
  const float* m2b2 = (const float*)d_in[15];
  const float* n2g  = (const float*)d_in[16];
  const float* n2b  = (const float*)d_in[17];
  const float* wih  = (const float*)d_in[18];
  const float* whh  = (const float*)d_in[19];
  const float* bih  = (const float*)d_in[20];
  const float* bhh  = (const float*)d_in[21];
  const float* opw  = (const float*)d_in[22];
  const float* opb  = (const float*)d_in[23];
  const float* c1w  = (const float*)d_in[24];
  const float* c1b  = (const float*)d_in[25];
  const float* c2w  = (const float*)d_in[26];
  const float* c2b  = (const float*)d_in[27];
  const float* pqw  = (const float*)d_in[28];
  const float* pqb  = (const float*)d_in[29];
  const float* pkw  = (const float*)d_in[30];
  const float* pkb  = (const float*)d_in[31];
  float* out = (float*)d_out;
  const int B = in_sizes[1];

  prep_frag<<<66, 256, 0, stream>>>(ne_w, m1w1, m1w2, m2w1, m2w2,
                                    wih, whh, pqw, opw, c1w, c2w, pkw);
  msp_mfma<<<B / 16, 512, 0, stream>>>(nf, nnp, rnn, poh, ne_b,
                                       m1b1, m1b2, n1g, n1b,
                                       m2b1, m2b2, n2g, n2b,
                                       bih, bhh, opb, c1b, c2b,
                                       pqb, pkb, out, B);
}

// Round 5
// 662.405 us; speedup vs baseline: 2.3680x; 2.3680x over previous
//
#include <hip/hip_runtime.h>
#include <cstdint>

#define NM 20
#define HS 72          // hbuf/xbuf row stride in shorts (144 B, 16B-aligned)

typedef __attribute__((ext_vector_type(8))) short bf16x8;
typedef __attribute__((ext_vector_type(4))) float f32x4;

#define MFMA(A, Bf, C) __builtin_amdgcn_mfma_f32_16x16x32_bf16((A), (Bf), (C), 0, 0, 0)

// ---- fragment-packed weights (bf16), built by prep kernel every launch ----
#define F_NE    0        // 1c x 4nb   (K=16 pad 32, N=64)
#define F_M1W1  2048     // 4c x 4nb   (K=128, N=64)
#define F_M1W2  10240    // 2c x 4nb
#define F_M2W1  14336    // 4c x 4nb
#define F_M2W2  22528    // 2c x 4nb
#define F_WIH   26624    // 3c x 12nb  (K=72 pad 96, N=192)
#define F_WHH   45056    // 2c x 12nb  (K=64, N=192)
#define F_PQ    57344    // 2c x 4nb
#define F_PACK  61440    // 2c x 2nb   (K=64, N=28 pad 32: op|c1|c2)
#define F_PK    63488    // 2c x 4nb
#define F_TOTAL 67584

__device__ __align__(16) short g_fr[F_TOTAL];

__device__ __forceinline__ short bf16rn(float x) {
  unsigned u = __float_as_uint(x);
  u += 0x7fffu + ((u >> 16) & 1u);
  return (short)(u >> 16);
}
__device__ __forceinline__ float bf2f(short s) {
  return __uint_as_float(((unsigned)(unsigned short)s) << 16);
}

#define LDF(off) (*(const bf16x8*)(g_fr + (off) + lane * 8))

// ---------------- prep: pack weights into B-fragment lane order ----------------
#define BUILD(OFS, CH, NBL, GETEXPR)                                   \
  for (int i = t; i < (CH) * (NBL) * 512; i += T) {                    \
    int j = i & 7, ln = (i >> 3) & 63, f = i >> 9;                     \
    int c = f / (NBL), nb = f % (NBL);                                 \
    int k = c * 32 + ((ln >> 4)) * 8 + j;                              \
    int n = nb * 16 + (ln & 15);                                       \
    (void)c; (void)k; (void)n;                                         \
    g_fr[(OFS) + i] = bf16rn(GETEXPR);                                 \
  }

__global__ void __launch_bounds__(256)
prep_frag(const float* __restrict__ ne_w,
          const float* __restrict__ m1w1, const float* __restrict__ m1w2,
          const float* __restrict__ m2w1, const float* __restrict__ m2w2,
          const float* __restrict__ wih,  const float* __restrict__ whh,
          const float* __restrict__ pqw,  const float* __restrict__ opw,
          const float* __restrict__ c1w,  const float* __restrict__ c2w,
          const float* __restrict__ pkw)
{
  const int t = blockIdx.x * blockDim.x + threadIdx.x;
  const int T = gridDim.x * blockDim.x;
  BUILD(F_NE,   1, 4,  (k < 16 ? ne_w[n * 16 + k] : 0.f))
  BUILD(F_M1W1, 4, 4,  m1w1[n * 128 + k])
  BUILD(F_M1W2, 2, 4,  m1w2[n * 64 + k])
  BUILD(F_M2W1, 4, 4,  m2w1[n * 128 + k])
  BUILD(F_M2W2, 2, 4,  m2w2[n * 64 + k])
  BUILD(F_WIH,  3, 12, (k < 72 ? wih[n * 72 + k] : 0.f))
  BUILD(F_WHH,  2, 12, whh[n * 64 + k])
  BUILD(F_PQ,   2, 4,  pqw[n * 64 + k])
  BUILD(F_PACK, 2, 2,  (n < 8 ? opw[n * 64 + k]
                        : n < 18 ? c1w[(n - 8) * 64 + k]
                        : n < 28 ? c2w[(n - 18) * 64 + k] : 0.f))
  BUILD(F_PK,   2, 4,  pkw[n * 64 + k])
}

// ---------------- MP stage: wave owns nodes {wv, wv+4, ..., wv+16} ----------------
// t round-trip grouped (3 then 2 nodes) behind ONE lgkmcnt each; LN mean/var fused.
__device__ __forceinline__ void mp_stage(
    short (*hbuf)[16][HS], short* tscr_w, float* pbuf_w, short (*xbuf)[HS],
    int w1off, int w2off,
    const float* __restrict__ B1P, const float* __restrict__ B2P,
    const float* __restrict__ LGP, const float* __restrict__ LBP,
    const int* nnrow, int wv, int lane, int l15, int q)
{
  const f32x4 zf4 = {0.f, 0.f, 0.f, 0.f};
  bf16x8 w1f[2][4], w2f[2][4];
  #pragma unroll
  for (int c = 0; c < 2; c++)
    #pragma unroll
    for (int nb = 0; nb < 4; nb++) {
      w1f[c][nb] = LDF(w1off + (c * 4 + nb) * 512);
      w2f[c][nb] = LDF(w2off + (c * 4 + nb) * 512);
    }
  // node-invariant msg half of W1 (concat cols 64..127), once per stage
  bf16x8 am0 = *(const bf16x8*)&xbuf[l15][q * 8];
  bf16x8 am1 = *(const bf16x8*)&xbuf[l15][32 + q * 8];
  f32x4 tmsg[4];
  #pragma unroll
  for (int nb = 0; nb < 4; nb++) {
    f32x4 tt = MFMA(am0, LDF(w1off + (2 * 4 + nb) * 512), zf4);
    tmsg[nb] = MFMA(am1, LDF(w1off + (3 * 4 + nb) * 512), tt);
  }
  float b1v[4], b2v[4], lgv[4], lbv[4];
  #pragma unroll
  for (int nb = 0; nb < 4; nb++) {
    int cc = l15 + 16 * nb;
    b1v[nb] = B1P[cc]; b2v[nb] = B2P[cc];
    lgv[nb] = LGP[cc]; lbv[nb] = LBP[cc];
  }
  f32x4 macc[4];
  #pragma unroll
  for (int nb = 0; nb < 4; nb++) macc[nb] = zf4;

  #pragma unroll
  for (int g0 = 0; g0 < 5; g0 += 3) {
    const int gcnt = (g0 == 0) ? 3 : 2;
    // ---- pass A: W1 + ReLU -> t scratch (all nodes of group) ----
    #pragma unroll
    for (int j = 0; j < 3; j++) {
      if (j >= gcnt) break;
      int n = wv + 4 * (g0 + j);
      bf16x8 a0 = *(const bf16x8*)&hbuf[n][l15][q * 8];
      bf16x8 a1 = *(const bf16x8*)&hbuf[n][l15][32 + q * 8];
      short* td = tscr_w + j * (16 * HS);
      #pragma unroll
      for (int nb = 0; nb < 4; nb++) {
        f32x4 acc = MFMA(a0, w1f[0][nb], tmsg[nb]);
        acc = MFMA(a1, w1f[1][nb], acc);
        #pragma unroll
        for (int i = 0; i < 4; i++)
          td[(q * 4 + i) * HS + l15 + 16 * nb] =
            bf16rn(fmaxf(acc[i] + b1v[nb], 0.f));
      }
    }
    asm volatile("s_waitcnt lgkmcnt(0)" ::: "memory");
    // ---- pass B: W2 + residual + LN (fused mean/var) ----
    #pragma unroll
    for (int j = 0; j < 3; j++) {
      if (j >= gcnt) break;
      int n = wv + 4 * (g0 + j);
      short* td = tscr_w + j * (16 * HS);
      // residual reads (scalar, issued before the MFMAs to overlap)
      float h0v[4][4];
      #pragma unroll
      for (int i = 0; i < 4; i++)
        #pragma unroll
        for (int nb = 0; nb < 4; nb++)
          h0v[i][nb] = bf2f(hbuf[n][q * 4 + i][l15 + 16 * nb]);
      bf16x8 t0 = *(const bf16x8*)&td[l15 * HS + q * 8];
      bf16x8 t1 = *(const bf16x8*)&td[l15 * HS + 32 + q * 8];
      f32x4 h1[4];
      #pragma unroll
      for (int nb = 0; nb < 4; nb++) {
        f32x4 acc = MFMA(t0, w2f[0][nb], zf4);
        h1[nb]    = MFMA(t1, w2f[1][nb], acc);
      }
      #pragma unroll
      for (int i = 0; i < 4; i++) {
        float y[4]; float s = 0.f, ss = 0.f;
        #pragma unroll
        for (int nb = 0; nb < 4; nb++) {
          y[nb] = h1[nb][i] + b2v[nb] + h0v[i][nb];
          s += y[nb]; ss += y[nb] * y[nb];
        }
        // fused mean/E[x^2] reduction over the 16-lane group: one 4-step chain
        #pragma unroll
        for (int d = 1; d < 16; d <<= 1) {
          s  += __shfl_xor(s, d, 64);
          ss += __shfl_xor(ss, d, 64);
        }
        float mu = s * 0.015625f;
        float var = ss * 0.015625f - mu * mu;
        float rstd = rsqrtf(var + 1e-5f);
        float mfv = (n < nnrow[i]) ? 1.f : 0.f;
        #pragma unroll
        for (int nb = 0; nb < 4; nb++) {
          float hv = ((y[nb] - mu) * rstd * lgv[nb] + lbv[nb]) * mfv;
          hbuf[n][q * 4 + i][l15 + 16 * nb] = bf16rn(hv);
          macc[nb][i] += hv;
        }
      }
    }
  }
  asm volatile("s_waitcnt lgkmcnt(0)" ::: "memory");
  #pragma unroll
  for (int nb = 0; nb < 4; nb++)
    #pragma unroll
    for (int i = 0; i < 4; i++)
      pbuf_w[(q * 4 + i) * 68 + l15 + 16 * nb] = macc[nb][i];
}

// ---------------- main fused kernel: 16 batch / block, 4 waves ----------------
__global__ void __launch_bounds__(256)
msp_mfma(const float* __restrict__ nf, const int* __restrict__ nnp,
         const float* __restrict__ rnn, const float* __restrict__ poh,
         const float* __restrict__ ne_b,
         const float* __restrict__ m1b1, const float* __restrict__ m1b2,
         const float* __restrict__ n1g, const float* __restrict__ n1b,
         const float* __restrict__ m2b1, const float* __restrict__ m2b2,
         const float* __restrict__ n2g, const float* __restrict__ n2b,
         const float* __restrict__ bih, const float* __restrict__ bhh,
         const float* __restrict__ opb, const float* __restrict__ c1b,
         const float* __restrict__ c2b, const float* __restrict__ pqb,
         const float* __restrict__ pkb,
         float* __restrict__ out, int B)
{
  __shared__ __align__(16) short hbuf[NM][16][HS];   // 46080 B
  __shared__ __align__(16) short uni[4][3 * 16 * HS];// 27648 B (t-scratch ∪ pbuf ∪ gates ∪ qhead)
  __shared__ __align__(16) short xbuf[16][HS];       // 2304 B (msg/gv/ns)
  __shared__ int   nn_sh[16];
  __shared__ float inv_sh[16];

  const int tid  = threadIdx.x;
  const int wv   = tid >> 6;
  const int lane = tid & 63;
  const int l15  = lane & 15;
  const int q    = lane >> 4;
  const int b0   = blockIdx.x * 16;

  if (tid < 16) { int v = nnp[b0 + tid]; nn_sh[tid] = v; inv_sh[tid] = 1.0f / (float)v; }
  __syncthreads();

  int nnrow[4];
  #pragma unroll
  for (int i = 0; i < 4; i++) nnrow[i] = nn_sh[q * 4 + i];

  const f32x4 zf4 = {0.f, 0.f, 0.f, 0.f};
  float* pbuf_w = (float*)&uni[wv][0];   // per-wave [16][68] f32 partials

  // ================= stage E: h0 = nf @ ne_w^T + ne_b =================
  {
    f32x4 macc[4];
    #pragma unroll
    for (int nb = 0; nb < 4; nb++) macc[nb] = zf4;
    bf16x8 nef[4]; float neb[4];
    #pragma unroll
    for (int nb = 0; nb < 4; nb++) { nef[nb] = LDF(F_NE + nb * 512); neb[nb] = ne_b[l15 + 16 * nb]; }
    for (int n = wv; n < NM; n += 4) {
      bf16x8 a;
      #pragma unroll
      for (int j = 0; j < 8; j++) a[j] = 0;
      if (q < 2) {
        const float* p = nf + ((size_t)(b0 + l15) * NM + n) * 16 + q * 8;
        #pragma unroll
        for (int j = 0; j < 8; j++) a[j] = bf16rn(p[j]);
      }
      #pragma unroll
      for (int nb = 0; nb < 4; nb++) {
        f32x4 acc = MFMA(a, nef[nb], zf4);
        #pragma unroll
        for (int i = 0; i < 4; i++) {
          float v = acc[i] + neb[nb];
          hbuf[n][q * 4 + i][l15 + 16 * nb] = bf16rn(v);
          if (n < nnrow[i]) macc[nb][i] += v;
        }
      }
    }
    #pragma unroll
    for (int nb = 0; nb < 4; nb++)
      #pragma unroll
      for (int i = 0; i < 4; i++)
        pbuf_w[(q * 4 + i) * 68 + l15 + 16 * nb] = macc[nb][i];
  }

  #define REDUCE_TO_XBUF()                                                     \
    __syncthreads();                                                           \
    for (int idx = tid; idx < 1024; idx += 256) {                              \
      int r = idx >> 6, c = idx & 63;                                          \
      float s = ((float*)&uni[0][0])[r * 68 + c]                               \
              + ((float*)&uni[1][0])[r * 68 + c]                               \
              + ((float*)&uni[2][0])[r * 68 + c]                               \
              + ((float*)&uni[3][0])[r * 68 + c];                              \
      xbuf[r][c] = bf16rn(s * inv_sh[r]);                                      \
    }                                                                          \
    __syncthreads();

  REDUCE_TO_XBUF()   // msg1
  mp_stage(hbuf, &uni[wv][0], pbuf_w, xbuf, F_M1W1, F_M1W2,
           m1b1, m1b2, n1g, n1b, nnrow, wv, lane, l15, q);
  REDUCE_TO_XBUF()   // msg2
  mp_stage(hbuf, &uni[wv][0], pbuf_w, xbuf, F_M2W1, F_M2W2,
           m2b1, m2b2, n2g, n2b, nnrow, wv, lane, l15, q);
  REDUCE_TO_XBUF()   // graph_vec

  // ================= GRU: MFMA phase (12 tiles over 4 waves) =================
  short* gz = &uni[0][0];   // gates: Xb[0..7], Gi[0..3], Gh[0..3] tiles of [16][18]
  {
    bf16x8 ax0 = *(const bf16x8*)&xbuf[l15][q * 8];
    bf16x8 ax1 = *(const bf16x8*)&xbuf[l15][32 + q * 8];
    bf16x8 ax2, ah0, ah1;
    #pragma unroll
    for (int j = 0; j < 8; j++) ax2[j] = 0;
    if (q == 0) {
      const float* pp = poh + (size_t)(b0 + l15) * 8;
      #pragma unroll
      for (int j = 0; j < 8; j++) ax2[j] = bf16rn(pp[j]);
    }
    {
      const float* pr = rnn + (size_t)(b0 + l15) * 64;
      #pragma unroll
      for (int j = 0; j < 8; j++) { ah0[j] = bf16rn(pr[q * 8 + j]); ah1[j] = bf16rn(pr[32 + q * 8 + j]); }
    }
    #pragma unroll
    for (int r = 0; r < 3; r++) {
      int nb = wv + 4 * r;
      f32x4 a = MFMA(ax0, LDF(F_WIH + (0 * 12 + nb) * 512), zf4);
      a = MFMA(ax1, LDF(F_WIH + (1 * 12 + nb) * 512), a);
      a = MFMA(ax2, LDF(F_WIH + (2 * 12 + nb) * 512), a);
      f32x4 h = MFMA(ah0, LDF(F_WHH + (0 * 12 + nb) * 512), zf4);
      h = MFMA(ah1, LDF(F_WHH + (1 * 12 + nb) * 512), h);
      if (nb < 8) {
        #pragma unroll
        for (int i = 0; i < 4; i++)
          gz[nb * 288 + (q * 4 + i) * 18 + l15] = bf16rn(a[i] + h[i]);
      } else {
        #pragma unroll
        for (int i = 0; i < 4; i++) {
          gz[(nb) * 288 + (q * 4 + i) * 18 + l15]     = bf16rn(a[i]);   // Gi at tiles 8..11
          gz[(nb + 4) * 288 + (q * 4 + i) * 18 + l15] = bf16rn(h[i]);   // Gh at tiles 12..15
        }
      }
    }
  }
  __syncthreads();

  // ================= GRU: pointwise gates (1024 items / 256 threads) =================
  #pragma unroll
  for (int rep = 0; rep < 4; rep++) {
    int it = tid + rep * 256;
    int row = it >> 6, col = it & 63;
    int nb = col >> 4, c16 = col & 15;
    float Xr = bf2f(gz[nb * 288 + row * 18 + c16]) + bih[col] + bhh[col];
    float Xz = bf2f(gz[(4 + nb) * 288 + row * 18 + c16]) + bih[64 + col] + bhh[64 + col];
    float gn = bf2f(gz[(8 + nb) * 288 + row * 18 + c16]) + bih[128 + col];
    float hn = bf2f(gz[(12 + nb) * 288 + row * 18 + c16]) + bhh[128 + col];
    float r = 1.f / (1.f + expf(-Xr));
    float z = 1.f / (1.f + expf(-Xz));
    float ng = tanhf(gn + r * hn);
    float st = rnn[(size_t)(b0 + row) * 64 + col];
    float ns = (1.f - z) * ng + z * st;
    out[(size_t)B * 48 + (size_t)(b0 + row) * 64 + col] = ns;
    xbuf[row][col] = bf16rn(ns);
  }
  __syncthreads();

  // ================= heads: PQ (all waves), PACK (waves 0-1) =================
  float* qh = (float*)&uni[2][0];   // [16][68] f32 q-head (above gate region)
  {
    bf16x8 an0 = *(const bf16x8*)&xbuf[l15][q * 8];
    bf16x8 an1 = *(const bf16x8*)&xbuf[l15][32 + q * 8];
    {
      f32x4 a = MFMA(an0, LDF(F_PQ + (0 * 4 + wv) * 512), zf4);
      a = MFMA(an1, LDF(F_PQ + (1 * 4 + wv) * 512), a);
      float bias = pqb[l15 + 16 * wv];
      #pragma unroll
      for (int i = 0; i < 4; i++)
        qh[(q * 4 + i) * 68 + l15 + 16 * wv] = a[i] + bias;
    }
    if (wv < 2) {
      f32x4 a = MFMA(an0, LDF(F_PACK + (0 * 2 + wv) * 512), zf4);
      a = MFMA(an1, LDF(F_PACK + (1 * 2 + wv) * 512), a);
      int col = l15 + 16 * wv;
      float bias = col < 8 ? opb[col] : col < 18 ? c1b[col - 8] : col < 28 ? c2b[col - 18] : 0.f;
      #pragma unroll
      for (int i = 0; i < 4; i++) {
        int b = b0 + q * 4 + i; float v = a[i] + bias;
        if (col < 8)       out[(size_t)b * 8 + col] = v;
        else if (col < 18) out[(size_t)B * 8 + (size_t)b * 10 + (col - 8)] = v;
        else if (col < 28) out[(size_t)B * 18 + (size_t)b * 10 + (col - 18)] = v;
      }
    }
  }
  __syncthreads();

  // ================= pointer logits =================
  {
    bf16x8 pkf[2][4];
    #pragma unroll
    for (int c = 0; c < 2; c++)
      #pragma unroll
      for (int nb = 0; nb < 4; nb++) pkf[c][nb] = LDF(F_PK + (c * 4 + nb) * 512);
    float pkbv[4], qv[4][4];
    #pragma unroll
    for (int nb = 0; nb < 4; nb++) {
      pkbv[nb] = pkb[l15 + 16 * nb];
      #pragma unroll
      for (int i = 0; i < 4; i++) qv[nb][i] = qh[(q * 4 + i) * 68 + l15 + 16 * nb];
    }
    for (int n = wv; n < NM; n += 4) {
      bf16x8 a0 = *(const bf16x8*)&hbuf[n][l15][q * 8];
      bf16x8 a1 = *(const bf16x8*)&hbuf[n][l15][32 + q * 8];
      f32x4 kk[4];
      #pragma unroll
      for (int nb = 0; nb < 4; nb++) {
        f32x4 acc = MFMA(a0, pkf[0][nb], zf4);
        kk[nb]    = MFMA(a1, pkf[1][nb], acc);
      }
      #pragma unroll
      for (int i = 0; i < 4; i++) {
        float tt = 0.f;
        #pragma unroll
        for (int nb = 0; nb < 4; nb++) tt += qv[nb][i] * (kk[nb][i] + pkbv[nb]);
        tt += __shfl_xor(tt, 1, 64); tt += __shfl_xor(tt, 2, 64);
        tt += __shfl_xor(tt, 4, 64); tt += __shfl_xor(tt, 8, 64);
        if (l15 == 0) {
          int b = b0 + q * 4 + i;
          out[(size_t)B * 28 + (size_t)b * 20 + n] = (n < nnrow[i]) ? tt : -1e9f;
        }
      }
    }
  }
}

extern "C" void kernel_launch(void* const* d_in, const int* in_sizes, int n_in,
                              void* d_out, int out_size, void* d_ws, size_t ws_size,
                              hipStream_t stream)
{
  (void)n_in; (void)out_size; (void)d_ws; (void)ws_size;
  const float* nf   = (const float*)d_in[0];
  const int*   nnp  = (const int*)  d_in[1];
  const float* rnn  = (const float*)d_in[2];
  const float* poh  = (const float*)d_in[3];
  const float* ne_w = (const float*)d_in[4];
  const float* ne_b = (const float*)d_in[5];
  const float* m1w1 = (const float*)d_in[6];
  const float* m1b1 = (const float*)d_in[7];
  const float* m1w2 = (const float*)d_in[8];
  const float* m1b2 = (const float*)d_in[9];
  const float* n1g  = (const float*)d_in[10];
  const float* n1b  = (const float*)d_in[11];
  const float* m2w1 = (const float*)d_in[12];
  const float* m2b1 = (const float*)d_in[13];
  const float* m2w2 = (const float*)d_in[14];
  const float* m2b2 = (const float*)d_in[15];
  const float* n2g  = (const float*)d_in[16];
  const float* n2b  = (const float*)d_in[17];
  const float* wih  = (const float*)d_in[18];
  const float* whh  = (const float*)d_in[19];
  const float* bih  = (const float*)d_in[20];
  const float* bhh  = (const float*)d_in[21];
  const float* opw  = (const float*)d_in[22];
  const float* opb  = (const float*)d_in[23];
  const float* c1w  = (const float*)d_in[24];
  const float* c1b  = (const float*)d_in[25];
  const float* c2w  = (const float*)d_in[26];
  const float* c2b  = (const float*)d_in[27];
  const float* pqw  = (const float*)d_in[28];
  const float* pqb  = (const float*)d_in[29];
  const float* pkw  = (const float*)d_in[30];
  const float* pkb  = (const float*)d_in[31];
  float* out = (float*)d_out;
  const int B = in_sizes[1];

  prep_frag<<<66, 256, 0, stream>>>(ne_w, m1w1, m1w2, m2w1, m2w2,
                                    wih, whh, pqw, opw, c1w, c2w, pkw);
  msp_mfma<<<B / 16, 256, 0, stream>>>(nf, nnp, rnn, poh, ne_b,
                                       m1b1, m1b2, n1g, n1b,
                                       m2b1, m2b2, n2g, n2b,
                                       bih, bhh, opb, c1b, c2b,
                                       pqb, pkb, out, B);
}

// Round 6
// 579.631 us; speedup vs baseline: 2.7062x; 1.1428x over previous
//
#include <hip/hip_runtime.h>
#include <hip/hip_bf16.h>
#include <cstdint>

#define NM 20

typedef __attribute__((ext_vector_type(8))) short bf16x8;
typedef __attribute__((ext_vector_type(4))) float f32x4;
typedef __attribute__((ext_vector_type(4))) unsigned int u32x4;

union FU { bf16x8 h; u32x4 u; };

#define MFMA(A, Bf, C) __builtin_amdgcn_mfma_f32_16x16x32_bf16((A), (Bf), (C), 0, 0, 0)

// A-fragment-packed, ROW-PERMUTED weights (bf16), built by prep each launch.
// frag f at OFS + f*512 + lane*8 + j.
#define F_NE    0        // 4 frags  (4mb x 1kc, K=16 pad 32)
#define F_M1W1  2048     // 16       (4mb x 4kc, K=128)
#define F_M1W2  10240    // 8        (4mb x 2kc)
#define F_M2W1  14336    // 16
#define F_M2W2  22528    // 8
#define F_WIH   26624    // 36       (12mb x 3kc, K=72 pad 96)
#define F_WHH   45056    // 24       (12mb x 2kc)
#define F_PQ    57344    // 8        (identity rows)
#define F_PK    61440    // 8        (identity rows)
#define F_PACK  65536    // 4        (2mb x 2kc, rows = op|c1|c2 pad 32)
#define F_TOTAL 67584

__device__ __align__(16) short g_fr[F_TOTAL];

__device__ __forceinline__ short bf16rn(float x) {
  unsigned u = __float_as_uint(x);
  u += 0x7fffu + ((u >> 16) & 1u);
  return (short)(u >> 16);
}
__device__ __forceinline__ float bf2f(short s) {
  return __uint_as_float(((unsigned)(unsigned short)s) << 16);
}
__device__ __forceinline__ unsigned pk2(float lo, float hi) {
  __hip_bfloat162 t = __float22bfloat162_rn(float2{lo, hi});
  return *reinterpret_cast<unsigned*>(&t);
}
// slot permutation: C row r (=mb*16+qq*4+i) lands at slot s64(r); permuting weight
// rows by s64 makes the C-output the B-fragment of the next GEMM, register-locally.
__device__ __forceinline__ int s64(int r) {
  int mb = r >> 4, qq = (r >> 2) & 3, i = r & 3;
  return (mb >> 1) * 32 + qq * 8 + (mb & 1) * 4 + i;
}

#define LDF(off) (*(const bf16x8*)(g_fr + (off) + lane * 8))

// ---------------- prep: A-frags with row permutes ----------------
#define BUILDA(OFS, MB, KC, ROWX, GET)                                 \
  for (int idx = t; idx < (MB) * (KC) * 512; idx += T) {               \
    int j = idx & 7, ln = (idx >> 3) & 63, f = idx >> 9;               \
    int mb = f / (KC), kc = f % (KC);                                  \
    int m = mb * 16 + (ln & 15);                                       \
    int k = kc * 32 + (ln >> 4) * 8 + j;                               \
    int row = (ROWX);                                                  \
    (void)row; (void)k; (void)m;                                       \
    g_fr[(OFS) + idx] = bf16rn(GET);                                   \
  }

__global__ void __launch_bounds__(256)
prep_frag(const float* __restrict__ ne_w,
          const float* __restrict__ m1w1, const float* __restrict__ m1w2,
          const float* __restrict__ m2w1, const float* __restrict__ m2w2,
          const float* __restrict__ wih,  const float* __restrict__ whh,
          const float* __restrict__ pqw,  const float* __restrict__ opw,
          const float* __restrict__ c1w,  const float* __restrict__ c2w,
          const float* __restrict__ pkw)
{
  const int t = blockIdx.x * blockDim.x + threadIdx.x;
  const int T = gridDim.x * blockDim.x;
  BUILDA(F_NE,   4, 1, s64(m), (k < 16 ? ne_w[row * 16 + k] : 0.f))
  BUILDA(F_M1W1, 4, 4, s64(m), m1w1[row * 128 + k])
  BUILDA(F_M1W2, 4, 2, s64(m), m1w2[row * 64 + k])
  BUILDA(F_M2W1, 4, 4, s64(m), m2w1[row * 128 + k])
  BUILDA(F_M2W2, 4, 2, s64(m), m2w2[row * 64 + k])
  BUILDA(F_WIH, 12, 3, (m & 0xC0) | s64(m & 63), (k < 72 ? wih[row * 72 + k] : 0.f))
  BUILDA(F_WHH, 12, 2, (m & 0xC0) | s64(m & 63), whh[row * 64 + k])
  BUILDA(F_PQ,   4, 2, m, pqw[row * 64 + k])
  BUILDA(F_PK,   4, 2, m, pkw[row * 64 + k])
  BUILDA(F_PACK, 2, 2, m, (row < 8 ? opw[row * 64 + k]
                           : row < 18 ? c1w[(row - 8) * 64 + k]
                           : row < 28 ? c2w[(row - 18) * 64 + k] : 0.f))
}

// load 16 slot-indexed f32 consts: dst[c*8+j] = src[c*32 + q*8 + j]
__device__ __forceinline__ void ld16(float* dst, const float* src, int q) {
  const float4 a0 = *(const float4*)(src + q * 8);
  const float4 a1 = *(const float4*)(src + q * 8 + 4);
  const float4 a2 = *(const float4*)(src + 32 + q * 8);
  const float4 a3 = *(const float4*)(src + 32 + q * 8 + 4);
  dst[0] = a0.x; dst[1] = a0.y; dst[2] = a0.z; dst[3] = a0.w;
  dst[4] = a1.x; dst[5] = a1.y; dst[6] = a1.z; dst[7] = a1.w;
  dst[8] = a2.x; dst[9] = a2.y; dst[10] = a2.z; dst[11] = a2.w;
  dst[12] = a3.x; dst[13] = a3.y; dst[14] = a3.z; dst[15] = a3.w;
}
__device__ __forceinline__ void pack8(FU& f, const float* v) {
  f.u[0] = pk2(v[0], v[1]); f.u[1] = pk2(v[2], v[3]);
  f.u[2] = pk2(v[4], v[5]); f.u[3] = pk2(v[6], v[7]);
}

// ---------------- MP stage: 10 nodes, fully register-resident ----------------
__device__ __forceinline__ void mp_stage(
    FU hA[][2], float* macc_out, const FU* msgf,
    int w1off, int w2off,
    const float* __restrict__ b1, const float* __restrict__ b2,
    const float* __restrict__ lg, const float* __restrict__ lb,
    int nnv, int n0, int lane, int q)
{
  const f32x4 zf4 = {0.f, 0.f, 0.f, 0.f};
  bf16x8 w1A[4][2], w2A[4][2];
  #pragma unroll
  for (int mb = 0; mb < 4; mb++) {
    w1A[mb][0] = LDF(w1off + (mb * 4 + 0) * 512);
    w1A[mb][1] = LDF(w1off + (mb * 4 + 1) * 512);
    w2A[mb][0] = LDF(w2off + (mb * 2 + 0) * 512);
    w2A[mb][1] = LDF(w2off + (mb * 2 + 1) * 512);
  }
  f32x4 tmsg[4];
  #pragma unroll
  for (int mb = 0; mb < 4; mb++) {
    tmsg[mb] = MFMA(LDF(w1off + (mb * 4 + 2) * 512), msgf[0].h, zf4);
    tmsg[mb] = MFMA(LDF(w1off + (mb * 4 + 3) * 512), msgf[1].h, tmsg[mb]);
  }
  float b1v[16], b2v[16], lgv[16], lbv[16];
  ld16(b1v, b1, q); ld16(b2v, b2, q); ld16(lgv, lg, q); ld16(lbv, lb, q);

  #pragma unroll
  for (int t = 0; t < 10; t++) {
    const int n = n0 + t;
    f32x4 T[4];
    #pragma unroll
    for (int mb = 0; mb < 4; mb++) {
      T[mb] = MFMA(w1A[mb][0], hA[t][0].h, tmsg[mb]);
      T[mb] = MFMA(w1A[mb][1], hA[t][1].h, T[mb]);
    }
    FU tb[2];
    #pragma unroll
    for (int c = 0; c < 2; c++)
      #pragma unroll
      for (int w = 0; w < 4; w++) {
        int mb = 2 * c + (w >> 1), i0 = (w & 1) * 2;
        float lo = fmaxf(T[mb][i0]     + b1v[(mb >> 1) * 8 + (mb & 1) * 4 + i0],     0.f);
        float hi = fmaxf(T[mb][i0 + 1] + b1v[(mb >> 1) * 8 + (mb & 1) * 4 + i0 + 1], 0.f);
        tb[c].u[w] = pk2(lo, hi);
      }
    f32x4 H[4];
    #pragma unroll
    for (int mb = 0; mb < 4; mb++) {
      H[mb] = MFMA(w2A[mb][0], tb[0].h, zf4);
      H[mb] = MFMA(w2A[mb][1], tb[1].h, H[mb]);
    }
    float y[16]; float s = 0.f, ss = 0.f;
    #pragma unroll
    for (int k = 0; k < 16; k++) {
      int c = k >> 3, j = k & 7;
      float v = H[2 * c + (j >> 2)][j & 3] + b2v[k] + bf2f(hA[t][c].h[j]);
      y[k] = v; s += v; ss += v * v;
    }
    s += __shfl_xor(s, 16, 64); ss += __shfl_xor(ss, 16, 64);
    s += __shfl_xor(s, 32, 64); ss += __shfl_xor(ss, 32, 64);
    float mu = s * 0.015625f;
    float rstd = rsqrtf(ss * 0.015625f - mu * mu + 1e-5f);
    float mfv = (n < nnv) ? 1.f : 0.f;
    #pragma unroll
    for (int k = 0; k < 16; k++) {
      float hv = ((y[k] - mu) * rstd * lgv[k] + lbv[k]) * mfv;
      macc_out[k] += hv; y[k] = hv;
    }
    pack8(hA[t][0], y); pack8(hA[t][1], y + 8);
  }
}

// ---------------- main: 32 batch / block; 4 waves = 2 independent pairs ----------------
__global__ void __launch_bounds__(256, 1)
msp(const float* __restrict__ nf, const int* __restrict__ nnp,
    const float* __restrict__ rnn, const float* __restrict__ poh,
    const float* __restrict__ ne_b,
    const float* __restrict__ m1b1, const float* __restrict__ m1b2,
    const float* __restrict__ n1g, const float* __restrict__ n1b,
    const float* __restrict__ m2b1, const float* __restrict__ m2b2,
    const float* __restrict__ n2g, const float* __restrict__ n2b,
    const float* __restrict__ bih, const float* __restrict__ bhh,
    const float* __restrict__ opb, const float* __restrict__ c1b,
    const float* __restrict__ c2b, const float* __restrict__ pqb,
    const float* __restrict__ pkb,
    float* __restrict__ out, int B)
{
  __shared__ float exch[2][2][2][64][17];   // [region][pair][half][lane][16+pad]
  __shared__ u32x4 nsx[2][2][64];           // [pair][half][lane]

  const int tid = threadIdx.x;
  const int wv = tid >> 6, pair = wv >> 1, half = wv & 1;
  const int lane = tid & 63;
  const int l15 = lane & 15, q = lane >> 4;
  const int b0 = blockIdx.x * 32 + pair * 16;
  const int bb = b0 + l15;
  const int n0 = half * 10;

  const int nnv = nnp[bb];
  const float inv = 1.0f / (float)nnv;
  const f32x4 zf4 = {0.f, 0.f, 0.f, 0.f};

  FU hA[10][2];
  float mac0[16];
  #pragma unroll
  for (int k = 0; k < 16; k++) mac0[k] = 0.f;

  // ================= E: h0^T = ne_w' · x^T =================
  {
    bf16x8 neA[4];
    #pragma unroll
    for (int mb = 0; mb < 4; mb++) neA[mb] = LDF(F_NE + mb * 512);
    float neb[16]; ld16(neb, ne_b, q);
    #pragma unroll
    for (int t = 0; t < 10; t++) {
      const int n = n0 + t;
      FU bx;
      if (q < 2) {
        const float* p = nf + ((size_t)bb * NM + n) * 16 + q * 8;
        float4 x0 = *(const float4*)p, x1 = *(const float4*)(p + 4);
        bx.u[0] = pk2(x0.x, x0.y); bx.u[1] = pk2(x0.z, x0.w);
        bx.u[2] = pk2(x1.x, x1.y); bx.u[3] = pk2(x1.z, x1.w);
      } else {
        bx.u[0] = 0; bx.u[1] = 0; bx.u[2] = 0; bx.u[3] = 0;
      }
      f32x4 C[4];
      #pragma unroll
      for (int mb = 0; mb < 4; mb++) C[mb] = MFMA(neA[mb], bx.h, zf4);
      float hv[16];
      #pragma unroll
      for (int k = 0; k < 16; k++) {
        int c = k >> 3, j = k & 7;
        hv[k] = C[2 * c + (j >> 2)][j & 3] + neb[k];
        if (n < nnv) mac0[k] += hv[k];
      }
      pack8(hA[t][0], hv); pack8(hA[t][1], hv + 8);
    }
  }

  FU msgf[2];
  float tmp[16];
  // ---- msg1 exchange (region 0) ----
  #pragma unroll
  for (int k = 0; k < 16; k++) exch[0][pair][half][lane][k] = mac0[k];
  __syncthreads();
  #pragma unroll
  for (int k = 0; k < 16; k++) tmp[k] = (mac0[k] + exch[0][pair][half ^ 1][lane][k]) * inv;
  pack8(msgf[0], tmp); pack8(msgf[1], tmp + 8);

  float mac1[16];
  #pragma unroll
  for (int k = 0; k < 16; k++) mac1[k] = 0.f;
  mp_stage(hA, mac1, msgf, F_M1W1, F_M1W2, m1b1, m1b2, n1g, n1b, nnv, n0, lane, q);

  // ---- msg2 exchange (region 1) ----
  #pragma unroll
  for (int k = 0; k < 16; k++) exch[1][pair][half][lane][k] = mac1[k];
  __syncthreads();
  #pragma unroll
  for (int k = 0; k < 16; k++) tmp[k] = (mac1[k] + exch[1][pair][half ^ 1][lane][k]) * inv;
  pack8(msgf[0], tmp); pack8(msgf[1], tmp + 8);

  float mac2[16];
  #pragma unroll
  for (int k = 0; k < 16; k++) mac2[k] = 0.f;
  mp_stage(hA, mac2, msgf, F_M2W1, F_M2W2, m2b1, m2b2, n2g, n2b, nnv, n0, lane, q);

  // ---- graph_vec exchange (region 0; two barriers since msg1 have passed) ----
  #pragma unroll
  for (int k = 0; k < 16; k++) exch[0][pair][half][lane][k] = mac2[k];
  __syncthreads();
  #pragma unroll
  for (int k = 0; k < 16; k++) tmp[k] = (mac2[k] + exch[0][pair][half ^ 1][lane][k]) * inv;

  // ================= GRU (pair-split: half h owns gate-triples 2h, 2h+1) =================
  {
    FU gx[2]; pack8(gx[0], tmp); pack8(gx[1], tmp + 8);
    FU px;
    if (q == 0) {
      const float* pp = poh + (size_t)bb * 8;
      float4 p0 = *(const float4*)pp, p1 = *(const float4*)(pp + 4);
      px.u[0] = pk2(p0.x, p0.y); px.u[1] = pk2(p0.z, p0.w);
      px.u[2] = pk2(p1.x, p1.y); px.u[3] = pk2(p1.z, p1.w);
    } else { px.u[0] = 0; px.u[1] = 0; px.u[2] = 0; px.u[3] = 0; }
    float rv[16]; ld16(rv, rnn + (size_t)bb * 64, q);
    FU ah[2]; pack8(ah[0], rv); pack8(ah[1], rv + 8);

    float ns_[2][4];
    #pragma unroll
    for (int tl = 0; tl < 2; tl++) {
      const int tt = half * 2 + tl;
      f32x4 R = MFMA(LDF(F_WIH + (tt * 3 + 0) * 512), gx[0].h, zf4);
      R = MFMA(LDF(F_WIH + (tt * 3 + 1) * 512), gx[1].h, R);
      R = MFMA(LDF(F_WIH + (tt * 3 + 2) * 512), px.h, R);
      R = MFMA(LDF(F_WHH + (tt * 2 + 0) * 512), ah[0].h, R);
      R = MFMA(LDF(F_WHH + (tt * 2 + 1) * 512), ah[1].h, R);
      f32x4 Z = MFMA(LDF(F_WIH + ((4 + tt) * 3 + 0) * 512), gx[0].h, zf4);
      Z = MFMA(LDF(F_WIH + ((4 + tt) * 3 + 1) * 512), gx[1].h, Z);
      Z = MFMA(LDF(F_WIH + ((4 + tt) * 3 + 2) * 512), px.h, Z);
      Z = MFMA(LDF(F_WHH + ((4 + tt) * 2 + 0) * 512), ah[0].h, Z);
      Z = MFMA(LDF(F_WHH + ((4 + tt) * 2 + 1) * 512), ah[1].h, Z);
      f32x4 Ni = MFMA(LDF(F_WIH + ((8 + tt) * 3 + 0) * 512), gx[0].h, zf4);
      Ni = MFMA(LDF(F_WIH + ((8 + tt) * 3 + 1) * 512), gx[1].h, Ni);
      Ni = MFMA(LDF(F_WIH + ((8 + tt) * 3 + 2) * 512), px.h, Ni);
      f32x4 Nh = MFMA(LDF(F_WHH + ((8 + tt) * 2 + 0) * 512), ah[0].h, zf4);
      Nh = MFMA(LDF(F_WHH + ((8 + tt) * 2 + 1) * 512), ah[1].h, Nh);
      #pragma unroll
      for (int i = 0; i < 4; i++) {
        const int K = (tt >> 1) * 32 + (tt & 1) * 4 + i;
        const int d = q * 8 + K;
        float rr = 1.f / (1.f + expf(-(R[i] + bih[d] + bhh[d])));
        float zz = 1.f / (1.f + expf(-(Z[i] + bih[64 + d] + bhh[64 + d])));
        float ng = tanhf(Ni[i] + bih[128 + d] + rr * (Nh[i] + bhh[128 + d]));
        float st = rv[(tt >> 1) * 8 + (tt & 1) * 4 + i];
        float v = (1.f - zz) * ng + zz * st;
        out[(size_t)B * 48 + (size_t)bb * 64 + d] = v;
        ns_[tl][i] = v;
      }
    }
    FU nspk;
    #pragma unroll
    for (int w = 0; w < 4; w++)
      nspk.u[w] = pk2(ns_[w >> 1][(2 * w) & 3], ns_[w >> 1][(2 * w + 1) & 3]);
    nsx[pair][half][lane] = nspk.u;
  }
  __syncthreads();

  // ================= heads + pointer =================
  {
    FU an0, an1;
    an0.u = nsx[pair][0][lane];
    an1.u = nsx[pair][1][lane];
    // q = ns @ pq^T + pqb  (identity rows: C row = natural feat)
    float qv[16];
    #pragma unroll
    for (int mb = 0; mb < 4; mb++) {
      f32x4 Qc = MFMA(LDF(F_PQ + (mb * 2 + 0) * 512), an0.h, zf4);
      Qc = MFMA(LDF(F_PQ + (mb * 2 + 1) * 512), an1.h, Qc);
      #pragma unroll
      for (int i = 0; i < 4; i++) qv[mb * 4 + i] = Qc[i] + pqb[mb * 16 + q * 4 + i];
    }
    float qb = 0.f;
    #pragma unroll
    for (int mb = 0; mb < 4; mb++)
      #pragma unroll
      for (int i = 0; i < 4; i++) qb += qv[mb * 4 + i] * pkb[mb * 16 + q * 4 + i];
    qb += __shfl_xor(qb, 16, 64); qb += __shfl_xor(qb, 32, 64);

    if (half == 0) {   // op/c1/c2 packed head, one wave per pair
      #pragma unroll
      for (int mb2 = 0; mb2 < 2; mb2++) {
        f32x4 L = MFMA(LDF(F_PACK + (mb2 * 2 + 0) * 512), an0.h, zf4);
        L = MFMA(LDF(F_PACK + (mb2 * 2 + 1) * 512), an1.h, L);
        #pragma unroll
        for (int i = 0; i < 4; i++) {
          int o = mb2 * 16 + q * 4 + i;
          if (o < 8)       out[(size_t)bb * 8 + o] = L[i] + opb[o];
          else if (o < 18) out[(size_t)B * 8 + (size_t)bb * 10 + (o - 8)] = L[i] + c1b[o - 8];
          else if (o < 28) out[(size_t)B * 18 + (size_t)bb * 10 + (o - 18)] = L[i] + c2b[o - 18];
        }
      }
    }
    // pointer: k^T = pk_w·h^T per node; ptr = sum_f q_f k_f + qb
    bf16x8 pkA[4][2];
    #pragma unroll
    for (int mb = 0; mb < 4; mb++) {
      pkA[mb][0] = LDF(F_PK + (mb * 2 + 0) * 512);
      pkA[mb][1] = LDF(F_PK + (mb * 2 + 1) * 512);
    }
    #pragma unroll
    for (int t = 0; t < 10; t++) {
      const int n = n0 + t;
      float dt = 0.f;
      #pragma unroll
      for (int mb = 0; mb < 4; mb++) {
        f32x4 Kc = MFMA(pkA[mb][0], hA[t][0].h, zf4);
        Kc = MFMA(pkA[mb][1], hA[t][1].h, Kc);
        #pragma unroll
        for (int i = 0; i < 4; i++) dt += qv[mb * 4 + i] * Kc[i];
      }
      dt += __shfl_xor(dt, 16, 64); dt += __shfl_xor(dt, 32, 64);
      if (q == 0)
        out[(size_t)B * 28 + (size_t)bb * 20 + n] = (n < nnv) ? (dt + qb) : -1e9f;
    }
  }
}

extern "C" void kernel_launch(void* const* d_in, const int* in_sizes, int n_in,
                              void* d_out, int out_size, void* d_ws, size_t ws_size,
                              hipStream_t stream)
{
  (void)n_in; (void)out_size; (void)d_ws; (void)ws_size;
  const float* nf   = (const float*)d_in[0];
  const int*   nnp  = (const int*)  d_in[1];
  const float* rnn  = (const float*)d_in[2];
  const float* poh  = (const float*)d_in[3];
  const float* ne_w = (const float*)d_in[4];
  const float* ne_b = (const float*)d_in[5];
  const float* m1w1 = (const float*)d_in[6];
  const float* m1b1 = (const float*)d_in[7];
  const float* m1w2 = (const float*)d_in[8];
  const float* m1b2 = (const float*)d_in[9];
  const float* n1g  = (const float*)d_in[10];
  const float* n1b  = (const float*)d_in[11];
  const float* m2w1 = (const float*)d_in[12];
  const float* m2b1 = (const float*)d_in[13];
  const float* m2w2 = (const float*)d_in[14];
  const float* m2b2 = (const float*)d_in[15];
  const float* n2g  = (const float*)d_in[16];
  const float* n2b  = (const float*)d_in[17];
  const float* wih  = (const float*)d_in[18];
  const float* whh  = (const float*)d_in[19];
  const float* bih  = (const float*)d_in[20];
  const float* bhh  = (const float*)d_in[21];
  const float* opw  = (const float*)d_in[22];
  const float* opb  = (const float*)d_in[23];
  const float* c1w  = (const float*)d_in[24];
  const float* c1b  = (const float*)d_in[25];
  const float* c2w  = (const float*)d_in[26];
  const float* c2b  = (const float*)d_in[27];
  const float* pqw  = (const float*)d_in[28];
  const float* pqb  = (const float*)d_in[29];
  const float* pkw  = (const float*)d_in[30];
  const float* pkb  = (const float*)d_in[31];
  float* out = (float*)d_out;
  const int B = in_sizes[1];

  prep_frag<<<132, 256, 0, stream>>>(ne_w, m1w1, m1w2, m2w1, m2w2,
                                     wih, whh, pqw, opw, c1w, c2w, pkw);
  msp<<<B / 32, 256, 0, stream>>>(nf, nnp, rnn, poh, ne_b,
                                  m1b1, m1b2, n1g, n1b,
                                  m2b1, m2b2, n2g, n2b,
                                  bih, bhh, opb, c1b, c2b,
                                  pqb, pkb, out, B);
}

// Round 7
// 472.714 us; speedup vs baseline: 3.3183x; 1.2262x over previous
//
#include <hip/hip_runtime.h>
#include <hip/hip_bf16.h>
#include <cstdint>

#define NM 20

typedef __attribute__((ext_vector_type(8))) short bf16x8;
typedef __attribute__((ext_vector_type(4))) float f32x4;
typedef __attribute__((ext_vector_type(4))) unsigned int u32x4;

union FU { bf16x8 h; u32x4 u; };

#define MFMA(A, Bf, C) __builtin_amdgcn_mfma_f32_16x16x32_bf16((A), (Bf), (C), 0, 0, 0)

// A-fragment-packed, ROW-PERMUTED weights (bf16), built by prep each launch.
#define F_NE    0        // 4 frags  (4mb x 1kc, K=16 pad 32)
#define F_M1W1  2048     // 16       (4mb x 4kc, K=128)
#define F_M1W2  10240    // 8        (4mb x 2kc)
#define F_M2W1  14336    // 16
#define F_M2W2  22528    // 8
#define F_WIH   26624    // 36       (12mb x 3kc, K=72 pad 96)
#define F_WHH   45056    // 24       (12mb x 2kc)
#define F_PQ    57344    // 8        (identity rows)
#define F_PK    61440    // 8        (identity rows)
#define F_PACK  65536    // 4        (2mb x 2kc, rows = op|c1|c2 pad 32)
// bf16-packed bias/LN vectors (natural feature order, 64 each)
#define F_BNE   67584
#define F_B11   67648
#define F_B12   67712
#define F_G1    67776
#define F_L1    67840
#define F_B21   67904
#define F_B22   67968
#define F_G2    68032
#define F_L2    68096
#define F_TOTAL 68160

__device__ __align__(16) short g_fr[F_TOTAL];

__device__ __forceinline__ short bf16rn(float x) {
  unsigned u = __float_as_uint(x);
  u += 0x7fffu + ((u >> 16) & 1u);
  return (short)(u >> 16);
}
__device__ __forceinline__ float bf2f(short s) {
  return __uint_as_float(((unsigned)(unsigned short)s) << 16);
}
__device__ __forceinline__ unsigned pk2(float lo, float hi) {
  __hip_bfloat162 t = __float22bfloat162_rn(float2{lo, hi});
  return *reinterpret_cast<unsigned*>(&t);
}
// slot permutation: C row r (=mb*16+qq*4+i) lands at slot s64(r); permuting weight
// rows by s64 makes the C-output the B-fragment of the next GEMM, register-locally.
__device__ __forceinline__ int s64(int r) {
  int mb = r >> 4, qq = (r >> 2) & 3, i = r & 3;
  return (mb >> 1) * 32 + qq * 8 + (mb & 1) * 4 + i;
}

#define LDF(off) (*(const bf16x8*)(g_fr + (off) + lane * 8))
#define LDB(off, c) (*(const bf16x8*)(g_fr + (off) + (c) * 32 + q * 8))

// ---------------- prep ----------------
#define BUILDA(OFS, MB, KC, ROWX, GET)                                 \
  for (int idx = t; idx < (MB) * (KC) * 512; idx += T) {               \
    int j = idx & 7, ln = (idx >> 3) & 63, f = idx >> 9;               \
    int mb = f / (KC), kc = f % (KC);                                  \
    int m = mb * 16 + (ln & 15);                                       \
    int k = kc * 32 + (ln >> 4) * 8 + j;                               \
    int row = (ROWX);                                                  \
    (void)row; (void)k; (void)m;                                       \
    g_fr[(OFS) + idx] = bf16rn(GET);                                   \
  }

__global__ void __launch_bounds__(256)
prep_frag(const float* __restrict__ ne_w,
          const float* __restrict__ m1w1, const float* __restrict__ m1w2,
          const float* __restrict__ m2w1, const float* __restrict__ m2w2,
          const float* __restrict__ wih,  const float* __restrict__ whh,
          const float* __restrict__ pqw,  const float* __restrict__ opw,
          const float* __restrict__ c1w,  const float* __restrict__ c2w,
          const float* __restrict__ pkw,
          const float* __restrict__ ne_b,
          const float* __restrict__ m1b1, const float* __restrict__ m1b2,
          const float* __restrict__ n1g,  const float* __restrict__ n1b,
          const float* __restrict__ m2b1, const float* __restrict__ m2b2,
          const float* __restrict__ n2g,  const float* __restrict__ n2b)
{
  const int t = blockIdx.x * blockDim.x + threadIdx.x;
  const int T = gridDim.x * blockDim.x;
  BUILDA(F_NE,   4, 1, s64(m), (k < 16 ? ne_w[row * 16 + k] : 0.f))
  BUILDA(F_M1W1, 4, 4, s64(m), m1w1[row * 128 + k])
  BUILDA(F_M1W2, 4, 2, s64(m), m1w2[row * 64 + k])
  BUILDA(F_M2W1, 4, 4, s64(m), m2w1[row * 128 + k])
  BUILDA(F_M2W2, 4, 2, s64(m), m2w2[row * 64 + k])
  BUILDA(F_WIH, 12, 3, (m & 0xC0) | s64(m & 63), (k < 72 ? wih[row * 72 + k] : 0.f))
  BUILDA(F_WHH, 12, 2, (m & 0xC0) | s64(m & 63), whh[row * 64 + k])
  BUILDA(F_PQ,   4, 2, m, pqw[row * 64 + k])
  BUILDA(F_PK,   4, 2, m, pkw[row * 64 + k])
  BUILDA(F_PACK, 2, 2, m, (row < 8 ? opw[row * 64 + k]
                           : row < 18 ? c1w[(row - 8) * 64 + k]
                           : row < 28 ? c2w[(row - 18) * 64 + k] : 0.f))
  for (int i = t; i < 64; i += T) {
    g_fr[F_BNE + i] = bf16rn(ne_b[i]);
    g_fr[F_B11 + i] = bf16rn(m1b1[i]);
    g_fr[F_B12 + i] = bf16rn(m1b2[i]);
    g_fr[F_G1  + i] = bf16rn(n1g[i]);
    g_fr[F_L1  + i] = bf16rn(n1b[i]);
    g_fr[F_B21 + i] = bf16rn(m2b1[i]);
    g_fr[F_B22 + i] = bf16rn(m2b2[i]);
    g_fr[F_G2  + i] = bf16rn(n2g[i]);
    g_fr[F_L2  + i] = bf16rn(n2b[i]);
  }
}

__device__ __forceinline__ void pack8(FU& f, const float* v) {
  f.u[0] = pk2(v[0], v[1]); f.u[1] = pk2(v[2], v[3]);
  f.u[2] = pk2(v[4], v[5]); f.u[3] = pk2(v[6], v[7]);
}

// ---------------- MP stage: 5 nodes/wave, register-resident ----------------
__device__ __forceinline__ void mp_stage(
    FU hA[][2], float* macc_out, const FU* msgf,
    int w1off, int w2off, int b1o, int b2o, int lgo, int lbo,
    int nnv, int n0, int lane, int q)
{
  const f32x4 zf4 = {0.f, 0.f, 0.f, 0.f};
  bf16x8 w1A[4][2], w2A[4][2];
  #pragma unroll
  for (int mb = 0; mb < 4; mb++) {
    w1A[mb][0] = LDF(w1off + (mb * 4 + 0) * 512);
    w1A[mb][1] = LDF(w1off + (mb * 4 + 1) * 512);
    w2A[mb][0] = LDF(w2off + (mb * 2 + 0) * 512);
    w2A[mb][1] = LDF(w2off + (mb * 2 + 1) * 512);
  }
  f32x4 tmsg[4];
  #pragma unroll
  for (int mb = 0; mb < 4; mb++) {
    tmsg[mb] = MFMA(LDF(w1off + (mb * 4 + 2) * 512), msgf[0].h, zf4);
    tmsg[mb] = MFMA(LDF(w1off + (mb * 4 + 3) * 512), msgf[1].h, tmsg[mb]);
  }
  FU b1p[2], b2p[2], lgp[2], lbp[2];
  #pragma unroll
  for (int c = 0; c < 2; c++) {
    b1p[c].h = LDB(b1o, c); b2p[c].h = LDB(b2o, c);
    lgp[c].h = LDB(lgo, c); lbp[c].h = LDB(lbo, c);
  }

  #pragma unroll
  for (int t = 0; t < 5; t++) {
    const int n = n0 + t;
    f32x4 T[4];
    #pragma unroll
    for (int mb = 0; mb < 4; mb++) {
      T[mb] = MFMA(w1A[mb][0], hA[t][0].h, tmsg[mb]);
      T[mb] = MFMA(w1A[mb][1], hA[t][1].h, T[mb]);
    }
    FU tb[2];
    #pragma unroll
    for (int c = 0; c < 2; c++)
      #pragma unroll
      for (int w = 0; w < 4; w++) {
        int mb = 2 * c + (w >> 1), i0 = (w & 1) * 2;
        float blo = bf2f(b1p[mb >> 1].h[(mb & 1) * 4 + i0]);
        float bhi = bf2f(b1p[mb >> 1].h[(mb & 1) * 4 + i0 + 1]);
        float lo = fmaxf(T[mb][i0]     + blo, 0.f);
        float hi = fmaxf(T[mb][i0 + 1] + bhi, 0.f);
        tb[c].u[w] = pk2(lo, hi);
      }
    f32x4 H[4];
    #pragma unroll
    for (int mb = 0; mb < 4; mb++) {
      H[mb] = MFMA(w2A[mb][0], tb[0].h, zf4);
      H[mb] = MFMA(w2A[mb][1], tb[1].h, H[mb]);
    }
    float y[16]; float s = 0.f, ss = 0.f;
    #pragma unroll
    for (int k = 0; k < 16; k++) {
      int c = k >> 3, j = k & 7;
      float v = H[2 * c + (j >> 2)][j & 3] + bf2f(b2p[c].h[j]) + bf2f(hA[t][c].h[j]);
      y[k] = v; s += v; ss += v * v;
    }
    s += __shfl_xor(s, 16, 64); ss += __shfl_xor(ss, 16, 64);
    s += __shfl_xor(s, 32, 64); ss += __shfl_xor(ss, 32, 64);
    float mu = s * 0.015625f;
    float rstd = rsqrtf(ss * 0.015625f - mu * mu + 1e-5f);
    float mfv = (n < nnv) ? 1.f : 0.f;
    #pragma unroll
    for (int k = 0; k < 16; k++) {
      int c = k >> 3, j = k & 7;
      float hv = ((y[k] - mu) * rstd * bf2f(lgp[c].h[j]) + bf2f(lbp[c].h[j])) * mfv;
      macc_out[k] += hv; y[k] = hv;
    }
    pack8(hA[t][0], y); pack8(hA[t][1], y + 8);
  }
}

// ---------------- main: 16 batch / block, 4 waves each own 5 nodes ----------------
__global__ void __launch_bounds__(256)
msp(const float* __restrict__ nf, const int* __restrict__ nnp,
    const float* __restrict__ rnn, const float* __restrict__ poh,
    const float* __restrict__ bih, const float* __restrict__ bhh,
    const float* __restrict__ opb, const float* __restrict__ c1b,
    const float* __restrict__ c2b, const float* __restrict__ pqb,
    const float* __restrict__ pkb,
    float* __restrict__ out, int B)
{
  __shared__ __align__(16) float exch[2][4][64][17];   // 34816 B
  __shared__ __align__(16) unsigned nsx[64][8];        // 2048 B

  const int tid = threadIdx.x;
  const int wv = tid >> 6;
  const int lane = tid & 63;
  const int l15 = lane & 15, q = lane >> 4;
  const int b0 = blockIdx.x * 16;
  const int bb = b0 + l15;
  const int n0 = wv * 5;

  const int nnv = nnp[bb];
  const float inv = 1.0f / (float)nnv;
  const f32x4 zf4 = {0.f, 0.f, 0.f, 0.f};

  FU hA[5][2];
  float mac[16];
  #pragma unroll
  for (int k = 0; k < 16; k++) mac[k] = 0.f;

  // ================= E: h0^T = ne_w' · x^T =================
  {
    bf16x8 neA[4];
    #pragma unroll
    for (int mb = 0; mb < 4; mb++) neA[mb] = LDF(F_NE + mb * 512);
    FU nep[2];
    nep[0].h = LDB(F_BNE, 0); nep[1].h = LDB(F_BNE, 1);
    #pragma unroll
    for (int t = 0; t < 5; t++) {
      const int n = n0 + t;
      FU bx;
      if (q < 2) {
        const float* p = nf + ((size_t)bb * NM + n) * 16 + q * 8;
        float4 x0 = *(const float4*)p, x1 = *(const float4*)(p + 4);
        bx.u[0] = pk2(x0.x, x0.y); bx.u[1] = pk2(x0.z, x0.w);
        bx.u[2] = pk2(x1.x, x1.y); bx.u[3] = pk2(x1.z, x1.w);
      } else {
        bx.u[0] = 0; bx.u[1] = 0; bx.u[2] = 0; bx.u[3] = 0;
      }
      f32x4 C[4];
      #pragma unroll
      for (int mb = 0; mb < 4; mb++) C[mb] = MFMA(neA[mb], bx.h, zf4);
      float hv[16];
      #pragma unroll
      for (int k = 0; k < 16; k++) {
        int c = k >> 3, j = k & 7;
        hv[k] = C[2 * c + (j >> 2)][j & 3] + bf2f(nep[c].h[j]);
        if (n < nnv) mac[k] += hv[k];
      }
      pack8(hA[t][0], hv); pack8(hA[t][1], hv + 8);
    }
  }

  FU msgf[2];
  float tmp[16];
  #define EXCHANGE(REG)                                                        \
    _Pragma("unroll")                                                          \
    for (int k = 0; k < 16; k++) exch[REG][wv][lane][k] = mac[k];              \
    __syncthreads();                                                           \
    _Pragma("unroll")                                                          \
    for (int k = 0; k < 16; k++)                                               \
      tmp[k] = (exch[REG][0][lane][k] + exch[REG][1][lane][k] +                \
                exch[REG][2][lane][k] + exch[REG][3][lane][k]) * inv;

  EXCHANGE(0)   // msg1
  pack8(msgf[0], tmp); pack8(msgf[1], tmp + 8);
  #pragma unroll
  for (int k = 0; k < 16; k++) mac[k] = 0.f;
  mp_stage(hA, mac, msgf, F_M1W1, F_M1W2, F_B11, F_B12, F_G1, F_L1, nnv, n0, lane, q);

  EXCHANGE(1)   // msg2
  pack8(msgf[0], tmp); pack8(msgf[1], tmp + 8);
  #pragma unroll
  for (int k = 0; k < 16; k++) mac[k] = 0.f;
  mp_stage(hA, mac, msgf, F_M2W1, F_M2W2, F_B21, F_B22, F_G2, F_L2, nnv, n0, lane, q);

  EXCHANGE(0)   // graph_vec (region 0 safe to reuse: all reads done pre-stage2 barrier)

  // ================= GRU: wave wv owns gate tile tt = wv =================
  {
    FU gx[2]; pack8(gx[0], tmp); pack8(gx[1], tmp + 8);
    FU px;
    if (q == 0) {
      const float* pp = poh + (size_t)bb * 8;
      float4 p0 = *(const float4*)pp, p1 = *(const float4*)(pp + 4);
      px.u[0] = pk2(p0.x, p0.y); px.u[1] = pk2(p0.z, p0.w);
      px.u[2] = pk2(p1.x, p1.y); px.u[3] = pk2(p1.z, p1.w);
    } else { px.u[0] = 0; px.u[1] = 0; px.u[2] = 0; px.u[3] = 0; }
    const float* rr0 = rnn + (size_t)bb * 64;
    float rv[16];
    #pragma unroll
    for (int c = 0; c < 2; c++) {
      float4 a0 = *(const float4*)(rr0 + c * 32 + q * 8);
      float4 a1 = *(const float4*)(rr0 + c * 32 + q * 8 + 4);
      rv[c * 8 + 0] = a0.x; rv[c * 8 + 1] = a0.y; rv[c * 8 + 2] = a0.z; rv[c * 8 + 3] = a0.w;
      rv[c * 8 + 4] = a1.x; rv[c * 8 + 5] = a1.y; rv[c * 8 + 6] = a1.z; rv[c * 8 + 7] = a1.w;
    }
    FU ah[2]; pack8(ah[0], rv); pack8(ah[1], rv + 8);

    const int tt = wv;
    f32x4 R = MFMA(LDF(F_WIH + (tt * 3 + 0) * 512), gx[0].h, zf4);
    R = MFMA(LDF(F_WIH + (tt * 3 + 1) * 512), gx[1].h, R);
    R = MFMA(LDF(F_WIH + (tt * 3 + 2) * 512), px.h, R);
    R = MFMA(LDF(F_WHH + (tt * 2 + 0) * 512), ah[0].h, R);
    R = MFMA(LDF(F_WHH + (tt * 2 + 1) * 512), ah[1].h, R);
    f32x4 Z = MFMA(LDF(F_WIH + ((4 + tt) * 3 + 0) * 512), gx[0].h, zf4);
    Z = MFMA(LDF(F_WIH + ((4 + tt) * 3 + 1) * 512), gx[1].h, Z);
    Z = MFMA(LDF(F_WIH + ((4 + tt) * 3 + 2) * 512), px.h, Z);
    Z = MFMA(LDF(F_WHH + ((4 + tt) * 2 + 0) * 512), ah[0].h, Z);
    Z = MFMA(LDF(F_WHH + ((4 + tt) * 2 + 1) * 512), ah[1].h, Z);
    f32x4 Ni = MFMA(LDF(F_WIH + ((8 + tt) * 3 + 0) * 512), gx[0].h, zf4);
    Ni = MFMA(LDF(F_WIH + ((8 + tt) * 3 + 1) * 512), gx[1].h, Ni);
    Ni = MFMA(LDF(F_WIH + ((8 + tt) * 3 + 2) * 512), px.h, Ni);
    f32x4 Nh = MFMA(LDF(F_WHH + ((8 + tt) * 2 + 0) * 512), ah[0].h, zf4);
    Nh = MFMA(LDF(F_WHH + ((8 + tt) * 2 + 1) * 512), ah[1].h, Nh);
    float nsv[4];
    #pragma unroll
    for (int i = 0; i < 4; i++) {
      const int K = (tt >> 1) * 32 + (tt & 1) * 4 + i;
      const int d = q * 8 + K;
      float rr = 1.f / (1.f + expf(-(R[i] + bih[d] + bhh[d])));
      float zz = 1.f / (1.f + expf(-(Z[i] + bih[64 + d] + bhh[64 + d])));
      float ng = tanhf(Ni[i] + bih[128 + d] + rr * (Nh[i] + bhh[128 + d]));
      float st = rv[(tt >> 1) * 8 + (tt & 1) * 4 + i];
      float v = (1.f - zz) * ng + zz * st;
      out[(size_t)B * 48 + (size_t)bb * 64 + d] = v;
      nsv[i] = v;
    }
    // ns quarter -> LDS: dwords (tt>>1)*4 + (tt&1)*2 + {0,1}
    const int dw = (tt >> 1) * 4 + (tt & 1) * 2;
    nsx[lane][dw]     = pk2(nsv[0], nsv[1]);
    nsx[lane][dw + 1] = pk2(nsv[2], nsv[3]);
  }
  __syncthreads();

  // ================= heads + pointer =================
  {
    FU an0, an1;
    an0.u = *(const u32x4*)&nsx[lane][0];
    an1.u = *(const u32x4*)&nsx[lane][4];
    float qv[16];
    #pragma unroll
    for (int mb = 0; mb < 4; mb++) {
      f32x4 Qc = MFMA(LDF(F_PQ + (mb * 2 + 0) * 512), an0.h, zf4);
      Qc = MFMA(LDF(F_PQ + (mb * 2 + 1) * 512), an1.h, Qc);
      #pragma unroll
      for (int i = 0; i < 4; i++) qv[mb * 4 + i] = Qc[i] + pqb[mb * 16 + q * 4 + i];
    }
    float qb = 0.f;
    #pragma unroll
    for (int mb = 0; mb < 4; mb++)
      #pragma unroll
      for (int i = 0; i < 4; i++) qb += qv[mb * 4 + i] * pkb[mb * 16 + q * 4 + i];
    qb += __shfl_xor(qb, 16, 64); qb += __shfl_xor(qb, 32, 64);

    if (wv < 2) {   // op/c1/c2 packed head: wave wv does mb2 = wv
      f32x4 L = MFMA(LDF(F_PACK + (wv * 2 + 0) * 512), an0.h, zf4);
      L = MFMA(LDF(F_PACK + (wv * 2 + 1) * 512), an1.h, L);
      #pragma unroll
      for (int i = 0; i < 4; i++) {
        int o = wv * 16 + q * 4 + i;
        if (o < 8)       out[(size_t)bb * 8 + o] = L[i] + opb[o];
        else if (o < 18) out[(size_t)B * 8 + (size_t)bb * 10 + (o - 8)] = L[i] + c1b[o - 8];
        else if (o < 28) out[(size_t)B * 18 + (size_t)bb * 10 + (o - 18)] = L[i] + c2b[o - 18];
      }
    }
    bf16x8 pkA[4][2];
    #pragma unroll
    for (int mb = 0; mb < 4; mb++) {
      pkA[mb][0] = LDF(F_PK + (mb * 2 + 0) * 512);
      pkA[mb][1] = LDF(F_PK + (mb * 2 + 1) * 512);
    }
    #pragma unroll
    for (int t = 0; t < 5; t++) {
      const int n = n0 + t;
      float dt = 0.f;
      #pragma unroll
      for (int mb = 0; mb < 4; mb++) {
        f32x4 Kc = MFMA(pkA[mb][0], hA[t][0].h, zf4);
        Kc = MFMA(pkA[mb][1], hA[t][1].h, Kc);
        #pragma unroll
        for (int i = 0; i < 4; i++) dt += qv[mb * 4 + i] * Kc[i];
      }
      dt += __shfl_xor(dt, 16, 64); dt += __shfl_xor(dt, 32, 64);
      if (q == 0)
        out[(size_t)B * 28 + (size_t)bb * 20 + n] = (n < nnv) ? (dt + qb) : -1e9f;
    }
  }
}

extern "C" void kernel_launch(void* const* d_in, const int* in_sizes, int n_in,
                              void* d_out, int out_size, void* d_ws, size_t ws_size,
                              hipStream_t stream)
{
  (void)n_in; (void)out_size; (void)d_ws; (void)ws_size;
  const float* nf   = (const float*)d_in[0];
  const int*   nnp  = (const int*)  d_in[1];
  const float* rnn  = (const float*)d_in[2];
  const float* poh  = (const float*)d_in[3];
  const float* ne_w = (const float*)d_in[4];
  const float* ne_b = (const float*)d_in[5];
  const float* m1w1 = (const float*)d_in[6];
  const float* m1b1 = (const float*)d_in[7];
  const float* m1w2 = (const float*)d_in[8];
  const float* m1b2 = (const float*)d_in[9];
  const float* n1g  = (const float*)d_in[10];
  const float* n1b  = (const float*)d_in[11];
  const float* m2w1 = (const float*)d_in[12];
  const float* m2b1 = (const float*)d_in[13];
  const float* m2w2 = (const float*)d_in[14];
  const float* m2b2 = (const float*)d_in[15];
  const float* n2g  = (const float*)d_in[16];
  const float* n2b  = (const float*)d_in[17];
  const float* wih  = (const float*)d_in[18];
  const float* whh  = (const float*)d_in[19];
  const float* bih  = (const float*)d_in[20];
  const float* bhh  = (const float*)d_in[21];
  const float* opw  = (const float*)d_in[22];
  const float* opb  = (const float*)d_in[23];
  const float* c1w  = (const float*)d_in[24];
  const float* c1b  = (const float*)d_in[25];
  const float* c2w  = (const float*)d_in[26];
  const float* c2b  = (const float*)d_in[27];
  const float* pqw  = (const float*)d_in[28];
  const float* pqb  = (const float*)d_in[29];
  const float* pkw  = (const float*)d_in[30];
  const float* pkb  = (const float*)d_in[31];
  float* out = (float*)d_out;
  const int B = in_sizes[1];

  prep_frag<<<132, 256, 0, stream>>>(ne_w, m1w1, m1w2, m2w1, m2w2,
                                     wih, whh, pqw, opw, c1w, c2w, pkw,
                                     ne_b, m1b1, m1b2, n1g, n1b,
                                     m2b1, m2b2, n2g, n2b);
  msp<<<B / 16, 256, 0, stream>>>(nf, nnp, rnn, poh,
                                  bih, bhh, opb, c1b, c2b,
                                  pqb, pkb, out, B);
}